// Round 1
// baseline (294.403 us; speedup 1.0000x reference)
//
#include <hip/hip_runtime.h>
#include <hip/hip_bf16.h>
#include <cstdint>
#include <cstddef>

// Problem constants
#define B_    8
#define H_    8
#define BH_   64
#define S_    976     // sequence length
#define SP_   992     // padded S (multiple of 32) for PV k-dim
#define D_    64      // head dim
#define DM_   512     // d_model
#define L_    16      // max_len
#define H2_   61      // pooled conv height
#define KW_   25      // conv taps
#define EFF_  32      // effective (conv+pool) taps
#define PSTR  996     // LDS fp32 row stride for scores (bank-friendly, >= SP_)

typedef __attribute__((ext_vector_type(8))) short bf16x8;
typedef __attribute__((ext_vector_type(4))) float f32x4;

__device__ __forceinline__ short f2bf(float f) {
    union { float f; unsigned u; } v; v.f = f;
    unsigned u = v.u;
    u += 0x7fffu + ((u >> 16) & 1u);   // round-to-nearest-even
    return (short)(u >> 16);
}

// ---------------------------------------------------------------------------
// Kernel 1: fold conv(25) + avgpool(8) into one 32-tap filter per channel.
// wbar[tz][c][t] = (1/8) * sum_{j=max(0,t-24)}^{min(7,t)} w_tz[c, t-j]
// ---------------------------------------------------------------------------
__global__ __launch_bounds__(256) void wbar_kernel(
    const float* __restrict__ wq, const float* __restrict__ wk,
    const float* __restrict__ wv, float* __restrict__ wbar) {
    int idx = blockIdx.x * 256 + threadIdx.x;
    if (idx >= 3 * DM_ * EFF_) return;
    int t  = idx & 31;
    int c  = (idx >> 5) & 511;
    int tz = idx >> 14;
    const float* w = (tz == 0) ? wq : (tz == 1) ? wk : wv;
    int jlo = (t - 24 > 0) ? t - 24 : 0;
    int jhi = (t < 7) ? t : 7;
    float s = 0.f;
    for (int j = jlo; j <= jhi; ++j) s += w[c * KW_ + (t - j)];
    wbar[idx] = s * 0.125f;
}

// ---------------------------------------------------------------------------
// Kernel 2: projection. Block = (tensor tz, batch b, chunk of 8 channels).
// Stages x[b] (512x16 fp32 = 32KB) in LDS, computes pooled conv outputs,
// scatters to MFMA-friendly layouts:
//   q,k : [bh][s][d]  bf16 row-major
//   v   : [bh][d][s]  bf16 transposed, s padded to 992 (pad pre-zeroed)
// ---------------------------------------------------------------------------
__global__ __launch_bounds__(256) void proj_kernel(
    const float* __restrict__ qin, const float* __restrict__ kin,
    const float* __restrict__ vin, const float* __restrict__ wbar,
    short* __restrict__ qws, short* __restrict__ kws, short* __restrict__ vtws) {
    __shared__ float xl[DM_ * L_];   // 32 KB
    __shared__ float wl[8 * EFF_];   // 1 KB
    int blk = blockIdx.x;
    int c0  = (blk & 63) * 8;
    int b   = (blk >> 6) & 7;
    int tz  = blk >> 9;
    const float* x  = (tz == 0) ? qin : (tz == 1) ? kin : vin;
    const float* xb = x + b * DM_ * L_;
    for (int i = threadIdx.x; i < DM_ * L_; i += 256) xl[i] = xb[i];
    if (threadIdx.x < 8 * EFF_)
        wl[threadIdx.x] = wbar[tz * DM_ * EFF_ + c0 * EFF_ + threadIdx.x];
    __syncthreads();

    for (int idx = threadIdx.x; idx < 8 * S_; idx += 256) {
        int ci  = idx / S_;
        int rem = idx - ci * S_;
        int h2  = rem >> 4;
        int l   = rem & 15;
        const float* xp = &xl[(h2 * 8) * L_ + l];
        const float* wp = &wl[ci * EFF_];
        float acc = 0.f;
        #pragma unroll
        for (int t = 0; t < EFF_; ++t) acc = fmaf(xp[t * L_], wp[t], acc);
        int f    = (c0 + ci) * S_ + rem;     // flat (C,H2,L) index
        int s    = f >> 9;                   // / 512
        int head = (f >> 6) & 7;
        int dh   = f & 63;
        int bh   = b * H_ + head;
        short bv = f2bf(acc);
        if (tz == 0)      qws[((size_t)bh * S_ + s) * D_ + dh] = bv;
        else if (tz == 1) kws[((size_t)bh * S_ + s) * D_ + dh] = bv;
        else              vtws[((size_t)bh * D_ + dh) * SP_ + s] = bv;
    }
}

// ---------------------------------------------------------------------------
// Kernel 3: fused attention. Block = (bh, 16-row Q tile). 4 waves.
//   Phase 1: scores(16x976) = Q_tile @ K^T via mfma_f32_16x16x32_bf16 -> LDS
//   Phase 2: wave-parallel softmax (64 lanes per row); write attn to d_out
//   Phase 3: x_tile = P @ V via MFMA, P read from LDS (bf16 in-register),
//            V^T fragments are contiguous 16B global loads.
// ---------------------------------------------------------------------------
__global__ __launch_bounds__(256) void attn_kernel(
    const short* __restrict__ qws, const short* __restrict__ kws,
    const short* __restrict__ vtws, const float* __restrict__ w_out,
    const float* __restrict__ b_out, float* __restrict__ d_out) {
    __shared__ float sc[16 * PSTR];          // 63,744 B

    int bid  = blockIdx.x;
    int bh   = bid / H2_;        // 0..63
    int qt   = bid - bh * H2_;   // 0..60
    int s0   = qt * 16;
    int lane = threadIdx.x & 63;
    int w    = threadIdx.x >> 6; // wave 0..3
    int l16  = lane & 15;
    int ko   = (lane >> 4) * 8;  // k-offset of this lane's 8-elem fragment

    // zero the pad columns (976..991) once
    sc[(threadIdx.x >> 4) * PSTR + S_ + (threadIdx.x & 15)] = 0.f;

    // Q fragments (A-operand): row = lane%16, k = ko..ko+7 (+32 for chunk 1)
    const short* qb = qws + ((size_t)(bh * S_ + s0 + l16)) * D_ + ko;
    bf16x8 a0 = *(const bf16x8*)(qb);
    bf16x8 a1 = *(const bf16x8*)(qb + 32);

    // ---- Phase 1: scores ----
    for (int ct = w; ct < H2_; ct += 4) {
        int n0 = ct * 16;
        const short* kb = kws + ((size_t)(bh * S_ + n0 + l16)) * D_ + ko;
        bf16x8 b0 = *(const bf16x8*)(kb);
        bf16x8 b1 = *(const bf16x8*)(kb + 32);
        f32x4 acc = {0.f, 0.f, 0.f, 0.f};
        acc = __builtin_amdgcn_mfma_f32_16x16x32_bf16(a0, b0, acc, 0, 0, 0);
        acc = __builtin_amdgcn_mfma_f32_16x16x32_bf16(a1, b1, acc, 0, 0, 0);
        #pragma unroll
        for (int i = 0; i < 4; ++i)
            sc[((lane >> 4) * 4 + i) * PSTR + n0 + l16] = acc[i];
    }
    __syncthreads();

    // ---- Phase 2: softmax over each row (scaled by 1/8), write attn ----
    const float scale = 0.125f;
    float wo = w_out[0], bo = b_out[0];
    size_t attn_base = 3997696ull + ((size_t)bh * S_ + s0) * S_;
    for (int rr = 0; rr < 4; ++rr) {
        int r = w * 4 + rr;
        float* row = &sc[r * PSTR];
        float m = -1e30f;
        for (int i = lane; i < S_; i += 64) m = fmaxf(m, row[i]);
        #pragma unroll
        for (int off = 32; off; off >>= 1) m = fmaxf(m, __shfl_xor(m, off));
        float sum = 0.f;
        for (int i = lane; i < S_; i += 64) {
            float p = __expf((row[i] - m) * scale);
            row[i] = p;
            sum += p;
        }
        #pragma unroll
        for (int off = 32; off; off >>= 1) sum += __shfl_xor(sum, off);
        float inv = 1.f / sum;
        float* gout = d_out + attn_base + (size_t)r * S_;
        for (int i = lane; i < S_; i += 64) {
            float a = row[i] * inv;
            row[i] = a;          // keep normalized P in LDS for PV
            gout[i] = a;         // coalesced 256B global writes
        }
    }
    __syncthreads();

    // ---- Phase 3: x_tile = P @ V  (wave w owns d-columns w*16..w*16+15) ----
    f32x4 acc = {0.f, 0.f, 0.f, 0.f};
    const short* vb = vtws + ((size_t)bh * D_ + (w * 16 + l16)) * SP_ + ko;
    const float* pp = &sc[l16 * PSTR + ko];
    for (int kk = 0; kk < SP_; kk += 32) {
        bf16x8 af;
        #pragma unroll
        for (int j = 0; j < 8; ++j) af[j] = f2bf(pp[kk + j]);
        bf16x8 bv = *(const bf16x8*)(vb + kk);
        acc = __builtin_amdgcn_mfma_f32_16x16x32_bf16(af, bv, acc, 0, 0, 0);
    }
    int b = bh >> 3, h = bh & 7;
    #pragma unroll
    for (int i = 0; i < 4; ++i) {
        int r = (lane >> 4) * 4 + i;
        d_out[((size_t)b * S_ + s0 + r) * DM_ + h * D_ + w * 16 + l16] =
            acc[i] * wo + bo;
    }
}

// ---------------------------------------------------------------------------
extern "C" void kernel_launch(void* const* d_in, const int* in_sizes, int n_in,
                              void* d_out, int out_size, void* d_ws, size_t ws_size,
                              hipStream_t stream) {
    const float* q   = (const float*)d_in[0];
    const float* k   = (const float*)d_in[1];
    const float* v   = (const float*)d_in[2];
    const float* wq  = (const float*)d_in[3];
    const float* wk  = (const float*)d_in[4];
    const float* wv  = (const float*)d_in[5];
    const float* wo  = (const float*)d_in[6];
    const float* bo  = (const float*)d_in[7];

    // workspace layout (bytes):
    //   wbar : 3*512*32*4            = 196,608
    //   qws  : 64*976*64*2           = 7,995,392
    //   kws  : 64*976*64*2           = 7,995,392
    //   vtws : 64*64*992*2           = 8,126,464
    char* ws = (char*)d_ws;
    float* wbar = (float*)ws;
    short* qws  = (short*)(ws + 196608);
    short* kws  = qws + (size_t)BH_ * S_ * D_;
    short* vtws = kws + (size_t)BH_ * S_ * D_;

    // zero V^T (covers the 976..991 pad); proj overwrites the live part
    hipMemsetAsync(vtws, 0, (size_t)BH_ * D_ * SP_ * sizeof(short), stream);

    wbar_kernel<<<192, 256, 0, stream>>>(wq, wk, wv, wbar);
    proj_kernel<<<1536, 256, 0, stream>>>(q, k, v, wbar, qws, kws, vtws);
    attn_kernel<<<BH_ * H2_, 256, 0, stream>>>(qws, kws, vtws, wo, bo,
                                               (float*)d_out);
}

// Round 2
// 205.711 us; speedup vs baseline: 1.4311x; 1.4311x over previous
//
#include <hip/hip_runtime.h>
#include <hip/hip_bf16.h>
#include <cstdint>
#include <cstddef>

// Problem constants
#define B_    8
#define H_    8
#define BH_   64
#define S_    976     // sequence length
#define SP_   992     // padded S (multiple of 32) for PV k-dim
#define D_    64      // head dim
#define DM_   512     // d_model
#define L_    16      // max_len
#define H2_   61      // pooled conv height
#define KW_   25      // conv taps
#define EFF_  32      // effective (conv+pool) taps
#define XOFF  3997696 // x output elements = 8*976*512; attn follows

typedef __attribute__((ext_vector_type(8))) short bf16x8;
typedef __attribute__((ext_vector_type(4))) short s16x4;
typedef __attribute__((ext_vector_type(4))) float f32x4;

__device__ __forceinline__ short f2bf(float f) {
    union { float f; unsigned u; } v; v.f = f;
    unsigned u = v.u;
    u += 0x7fffu + ((u >> 16) & 1u);   // round-to-nearest-even
    return (short)(u >> 16);
}

// ---------------------------------------------------------------------------
// Kernel 1: fold conv(25) + avgpool(8) into one 32-tap filter per channel.
// ---------------------------------------------------------------------------
__global__ __launch_bounds__(256) void wbar_kernel(
    const float* __restrict__ wq, const float* __restrict__ wk,
    const float* __restrict__ wv, float* __restrict__ wbar) {
    int idx = blockIdx.x * 256 + threadIdx.x;
    if (idx >= 3 * DM_ * EFF_) return;
    int t  = idx & 31;
    int c  = (idx >> 5) & 511;
    int tz = idx >> 14;
    const float* w = (tz == 0) ? wq : (tz == 1) ? wk : wv;
    int jlo = (t - 24 > 0) ? t - 24 : 0;
    int jhi = (t < 7) ? t : 7;
    float s = 0.f;
    for (int j = jlo; j <= jhi; ++j) s += w[c * KW_ + (t - j)];
    wbar[idx] = s * 0.125f;
}

// ---------------------------------------------------------------------------
// Kernel 2: projection, register-blocked.
// Block = (tz, b, 32-channel group). Thread = (channel, lane-of-8).
// Each x-load feeds 4 outputs (window overlap of the stride-8, width-32 conv).
// Weights live in 32 VGPRs. LDS reads: 16-lane broadcast, conflict-free.
// ---------------------------------------------------------------------------
__global__ __launch_bounds__(256) void proj_kernel(
    const float* __restrict__ qin, const float* __restrict__ kin,
    const float* __restrict__ vin, const float* __restrict__ wbar,
    short* __restrict__ qws, short* __restrict__ kws, short* __restrict__ vtws) {
    __shared__ float xl[536 * L_];   // 512 live channels + 24 zero-pad rows
    int blk = blockIdx.x;            // grid = 3*8*16 = 384
    int cg  = blk & 15;
    int b   = (blk >> 4) & 7;
    int tz  = blk >> 7;
    const float* x = (tz == 0) ? qin : (tz == 1) ? kin : vin;

    const float4* xb4 = (const float4*)(x + b * DM_ * L_);
    float4* xl4 = (float4*)xl;
    for (int i = threadIdx.x; i < DM_ * L_ / 4; i += 256) xl4[i] = xb4[i];
    for (int i = DM_ * L_ + threadIdx.x; i < 536 * L_; i += 256) xl[i] = 0.f;

    int c_local = threadIdx.x >> 3;          // 0..31
    int plane   = threadIdx.x & 7;
    int c       = cg * 32 + c_local;         // 0..511
    float wreg[EFF_];
    const float4* wb4 = (const float4*)(wbar + ((size_t)tz * DM_ + c) * EFF_);
    #pragma unroll
    for (int i = 0; i < 8; ++i) {
        float4 t4 = wb4[i];
        wreg[4*i+0] = t4.x; wreg[4*i+1] = t4.y;
        wreg[4*i+2] = t4.z; wreg[4*i+3] = t4.w;
    }
    __syncthreads();

    for (int m = 0; m < 32; ++m) {
        int pg  = plane + 8 * m;   // position group: 4 h2 rows x 1 l
        int h2b = pg >> 4;         // 0..15
        int l   = pg & 15;
        float acc[4] = {0.f, 0.f, 0.f, 0.f};
        #pragma unroll
        for (int k = 0; k < 56; ++k) {
            float xv = xl[(h2b * 32 + k) * L_ + l];
            #pragma unroll
            for (int d = 0; d < 4; ++d) {
                int t = k - 8 * d;
                if (t >= 0 && t < EFF_) acc[d] = fmaf(xv, wreg[t], acc[d]);
            }
        }
        #pragma unroll
        for (int d = 0; d < 4; ++d) {
            int h2 = h2b * 4 + d;
            if (h2 < H2_) {
                int f    = c * S_ + h2 * L_ + l;
                int s    = f >> 9;
                int head = (f >> 6) & 7;
                int dh   = f & 63;
                int bh   = b * H_ + head;
                short bv = f2bf(acc[d]);
                if (tz == 0)      qws[((size_t)bh * S_ + s) * D_ + dh] = bv;
                else if (tz == 1) kws[((size_t)bh * S_ + s) * D_ + dh] = bv;
                else              vtws[((size_t)bh * D_ + dh) * SP_ + s] = bv;
            }
        }
    }
}

// ---------------------------------------------------------------------------
// Kernel 3: attention, register-resident flash. One WAVE per (bh, 16-q tile).
// Swapped QK^T: mfma(K_rows, Q_rows) -> D[key][query], query = lane&15.
// Pass 1: Z = row sums (no max subtract; logits ~ +-1). Pass 2: recompute,
// write normalized attn (float4), repack P via 1.25KB/wave LDS, PV MFMA.
// No __syncthreads anywhere; waves fully independent.
// ---------------------------------------------------------------------------
__global__ __launch_bounds__(256) void attn_kernel(
    const short* __restrict__ qws, const short* __restrict__ kws,
    const short* __restrict__ vtws, const float* __restrict__ w_out,
    const float* __restrict__ b_out, float* __restrict__ out) {
    __shared__ short plds[4][16 * 40];       // per-wave P repack, stride 40 bf16
    int w    = threadIdx.x >> 6;
    int lane = threadIdx.x & 63;
    int l16  = lane & 15;
    int g    = lane >> 4;
    int bh   = blockIdx.x >> 4;
    int qt   = (blockIdx.x & 15) * 4 + w;
    if (qt >= H2_) return;                   // wave-uniform; no barriers below
    int s0 = qt * 16;

    const short* qb = qws + ((size_t)bh * S_ + s0 + l16) * D_ + g * 8;
    bf16x8 q0 = *(const bf16x8*)qb;
    bf16x8 q1 = *(const bf16x8*)(qb + 32);
    const short* kbase = kws + ((size_t)bh * S_ + l16) * D_ + g * 8;

    // ---- pass 1: Z ----
    float sa = 0.f, sb = 0.f, sc_ = 0.f, sd = 0.f;
    for (int ct = 0; ct < H2_; ++ct) {
        const short* kb = kbase + (size_t)ct * 16 * D_;
        bf16x8 k0 = *(const bf16x8*)kb;
        bf16x8 k1 = *(const bf16x8*)(kb + 32);
        f32x4 acc = {0.f, 0.f, 0.f, 0.f};
        acc = __builtin_amdgcn_mfma_f32_16x16x32_bf16(k0, q0, acc, 0, 0, 0);
        acc = __builtin_amdgcn_mfma_f32_16x16x32_bf16(k1, q1, acc, 0, 0, 0);
        sa += __expf(acc[0] * 0.125f);
        sb += __expf(acc[1] * 0.125f);
        sc_ += __expf(acc[2] * 0.125f);
        sd += __expf(acc[3] * 0.125f);
    }
    float sum = (sa + sb) + (sc_ + sd);
    sum += __shfl_xor(sum, 16);
    sum += __shfl_xor(sum, 32);
    float inv = 1.f / sum;

    float wo = w_out[0], bo = b_out[0];
    float* arow = out + XOFF + ((size_t)bh * S_ + s0 + l16) * S_;
    short* pl = &plds[w][0];
    const short* vrow = vtws + ((size_t)bh * D_ + l16) * SP_ + g * 8;

    f32x4 o0 = {0.f,0.f,0.f,0.f}, o1 = {0.f,0.f,0.f,0.f};
    f32x4 o2 = {0.f,0.f,0.f,0.f}, o3 = {0.f,0.f,0.f,0.f};

    // ---- pass 2: 30 full 32-key chunks ----
    for (int c = 0; c < 30; ++c) {
        #pragma unroll
        for (int t = 0; t < 2; ++t) {
            int ct = 2 * c + t;
            const short* kb = kbase + (size_t)ct * 16 * D_;
            bf16x8 k0 = *(const bf16x8*)kb;
            bf16x8 k1 = *(const bf16x8*)(kb + 32);
            f32x4 acc = {0.f, 0.f, 0.f, 0.f};
            acc = __builtin_amdgcn_mfma_f32_16x16x32_bf16(k0, q0, acc, 0, 0, 0);
            acc = __builtin_amdgcn_mfma_f32_16x16x32_bf16(k1, q1, acc, 0, 0, 0);
            float p0 = __expf(acc[0] * 0.125f) * inv;
            float p1 = __expf(acc[1] * 0.125f) * inv;
            float p2 = __expf(acc[2] * 0.125f) * inv;
            float p3 = __expf(acc[3] * 0.125f) * inv;
            float4 pv = {p0, p1, p2, p3};
            *(float4*)(arow + ct * 16 + g * 4) = pv;   // coalesced attn write
            s16x4 pk = {f2bf(p0), f2bf(p1), f2bf(p2), f2bf(p3)};
            *(s16x4*)(pl + l16 * 40 + t * 16 + g * 4) = pk;
        }
        __threadfence_block();                 // intra-wave LDS RAW ordering
        bf16x8 pa = *(const bf16x8*)(pl + l16 * 40 + g * 8);
        const short* vb = vrow + c * 32;
        o0 = __builtin_amdgcn_mfma_f32_16x16x32_bf16(pa, *(const bf16x8*)(vb), o0, 0, 0, 0);
        o1 = __builtin_amdgcn_mfma_f32_16x16x32_bf16(pa, *(const bf16x8*)(vb + 16 * SP_), o1, 0, 0, 0);
        o2 = __builtin_amdgcn_mfma_f32_16x16x32_bf16(pa, *(const bf16x8*)(vb + 32 * SP_), o2, 0, 0, 0);
        o3 = __builtin_amdgcn_mfma_f32_16x16x32_bf16(pa, *(const bf16x8*)(vb + 48 * SP_), o3, 0, 0, 0);
    }

    // ---- tail: tile 60 + zero phantom tile ----
    {
        const short* kb = kbase + (size_t)60 * 16 * D_;
        bf16x8 k0 = *(const bf16x8*)kb;
        bf16x8 k1 = *(const bf16x8*)(kb + 32);
        f32x4 acc = {0.f, 0.f, 0.f, 0.f};
        acc = __builtin_amdgcn_mfma_f32_16x16x32_bf16(k0, q0, acc, 0, 0, 0);
        acc = __builtin_amdgcn_mfma_f32_16x16x32_bf16(k1, q1, acc, 0, 0, 0);
        float p0 = __expf(acc[0] * 0.125f) * inv;
        float p1 = __expf(acc[1] * 0.125f) * inv;
        float p2 = __expf(acc[2] * 0.125f) * inv;
        float p3 = __expf(acc[3] * 0.125f) * inv;
        float4 pv = {p0, p1, p2, p3};
        *(float4*)(arow + 60 * 16 + g * 4) = pv;
        s16x4 pk = {f2bf(p0), f2bf(p1), f2bf(p2), f2bf(p3)};
        *(s16x4*)(pl + l16 * 40 + g * 4) = pk;
        s16x4 zz = {0, 0, 0, 0};
        *(s16x4*)(pl + l16 * 40 + 16 + g * 4) = zz;
        __threadfence_block();
        bf16x8 pa = *(const bf16x8*)(pl + l16 * 40 + g * 8);
        const short* vb = vrow + 960;          // keys 960..991 (V pad zeroed)
        o0 = __builtin_amdgcn_mfma_f32_16x16x32_bf16(pa, *(const bf16x8*)(vb), o0, 0, 0, 0);
        o1 = __builtin_amdgcn_mfma_f32_16x16x32_bf16(pa, *(const bf16x8*)(vb + 16 * SP_), o1, 0, 0, 0);
        o2 = __builtin_amdgcn_mfma_f32_16x16x32_bf16(pa, *(const bf16x8*)(vb + 32 * SP_), o2, 0, 0, 0);
        o3 = __builtin_amdgcn_mfma_f32_16x16x32_bf16(pa, *(const bf16x8*)(vb + 48 * SP_), o3, 0, 0, 0);
    }

    // ---- epilogue: x = O*wo + bo ----
    int b = bh >> 3, h = bh & 7;
    #pragma unroll
    for (int i = 0; i < 4; ++i) {
        float* xr = out + ((size_t)b * S_ + s0 + g * 4 + i) * DM_ + h * D_ + l16;
        xr[0]  = o0[i] * wo + bo;
        xr[16] = o1[i] * wo + bo;
        xr[32] = o2[i] * wo + bo;
        xr[48] = o3[i] * wo + bo;
    }
}

// ---------------------------------------------------------------------------
extern "C" void kernel_launch(void* const* d_in, const int* in_sizes, int n_in,
                              void* d_out, int out_size, void* d_ws, size_t ws_size,
                              hipStream_t stream) {
    const float* q   = (const float*)d_in[0];
    const float* k   = (const float*)d_in[1];
    const float* v   = (const float*)d_in[2];
    const float* wq  = (const float*)d_in[3];
    const float* wk  = (const float*)d_in[4];
    const float* wv  = (const float*)d_in[5];
    const float* wo  = (const float*)d_in[6];
    const float* bo  = (const float*)d_in[7];

    char* ws = (char*)d_ws;
    float* wbar = (float*)ws;
    short* qws  = (short*)(ws + 196608);
    short* kws  = qws + (size_t)BH_ * S_ * D_;
    short* vtws = kws + (size_t)BH_ * S_ * D_;

    // zero V^T (covers the 976..991 pad); proj overwrites the live part
    hipMemsetAsync(vtws, 0, (size_t)BH_ * D_ * SP_ * sizeof(short), stream);

    wbar_kernel<<<192, 256, 0, stream>>>(wq, wk, wv, wbar);
    proj_kernel<<<384, 256, 0, stream>>>(q, k, v, wbar, qws, kws, vtws);
    attn_kernel<<<BH_ * 16, 256, 0, stream>>>(qws, kws, vtws, wo, bo,
                                              (float*)d_out);
}

// Round 4
// 192.041 us; speedup vs baseline: 1.5330x; 1.0712x over previous
//
#include <hip/hip_runtime.h>
#include <hip/hip_bf16.h>
#include <cstdint>
#include <cstddef>

// Problem constants
#define B_    8
#define H_    8
#define BH_   64
#define S_    976     // sequence length
#define SP_   992     // padded S (multiple of 32) for PV k-dim
#define D_    64      // head dim
#define DM_   512     // d_model
#define L_    16      // max_len
#define H2_   61      // pooled conv height / q-tiles
#define KW_   25      // conv taps
#define EFF_  32      // effective (conv+pool) taps
#define XOFF  3997696 // x output elements = 8*976*512; attn follows
#define NWB   49152   // 3*512*32 wbar elements
#define OSTR  68      // olds row stride (floats) -> 2-way max bank aliasing

typedef __attribute__((ext_vector_type(8))) short bf16x8;
typedef __attribute__((ext_vector_type(4))) short s16x4;
typedef __attribute__((ext_vector_type(4))) float f32x4;

__device__ __forceinline__ short f2bf(float f) {
    union { float f; unsigned u; } v; v.f = f;
    unsigned u = v.u;
    u += 0x7fffu + ((u >> 16) & 1u);   // round-to-nearest-even
    return (short)(u >> 16);
}

// ---------------------------------------------------------------------------
// Kernel 1: fold conv(25)+avgpool(8) into 32-tap filter; spare blocks zero
// the V^T pad columns (s=976..991) so no hipMemsetAsync is needed.
// ---------------------------------------------------------------------------
__global__ __launch_bounds__(256) void wbar_kernel(
    const float* __restrict__ wq, const float* __restrict__ wk,
    const float* __restrict__ wv, float* __restrict__ wbar,
    short* __restrict__ vtws) {
    int idx = blockIdx.x * 256 + threadIdx.x;
    if (idx < NWB) {
        int t  = idx & 31;
        int c  = (idx >> 5) & 511;
        int tz = idx >> 14;
        const float* w = (tz == 0) ? wq : (tz == 1) ? wk : wv;
        int jlo = (t - 24 > 0) ? t - 24 : 0;
        int jhi = (t < 7) ? t : 7;
        float s = 0.f;
        for (int j = jlo; j <= jhi; ++j) s += w[c * KW_ + (t - j)];
        wbar[idx] = s * 0.125f;
    } else {
        int p = idx - NWB;                 // 0..65535
        int bh = p >> 10;
        int dh = (p >> 4) & 63;
        int s  = S_ + (p & 15);
        vtws[((size_t)bh * D_ + dh) * SP_ + s] = 0;
    }
}

// ---------------------------------------------------------------------------
// Kernel 2: projection, register-blocked.
// ---------------------------------------------------------------------------
__global__ __launch_bounds__(256) void proj_kernel(
    const float* __restrict__ qin, const float* __restrict__ kin,
    const float* __restrict__ vin, const float* __restrict__ wbar,
    short* __restrict__ qws, short* __restrict__ kws, short* __restrict__ vtws) {
    __shared__ float xl[536 * L_];
    int blk = blockIdx.x;            // grid = 3*8*16 = 384
    int cg  = blk & 15;
    int b   = (blk >> 4) & 7;
    int tz  = blk >> 7;
    const float* x = (tz == 0) ? qin : (tz == 1) ? kin : vin;

    const float4* xb4 = (const float4*)(x + b * DM_ * L_);
    float4* xl4 = (float4*)xl;
    for (int i = threadIdx.x; i < DM_ * L_ / 4; i += 256) xl4[i] = xb4[i];
    for (int i = DM_ * L_ + threadIdx.x; i < 536 * L_; i += 256) xl[i] = 0.f;

    int c_local = threadIdx.x >> 3;
    int plane   = threadIdx.x & 7;
    int c       = cg * 32 + c_local;
    float wreg[EFF_];
    const float4* wb4 = (const float4*)(wbar + ((size_t)tz * DM_ + c) * EFF_);
    #pragma unroll
    for (int i = 0; i < 8; ++i) {
        float4 t4 = wb4[i];
        wreg[4*i+0] = t4.x; wreg[4*i+1] = t4.y;
        wreg[4*i+2] = t4.z; wreg[4*i+3] = t4.w;
    }
    __syncthreads();

    for (int m = 0; m < 32; ++m) {
        int pg  = plane + 8 * m;
        int h2b = pg >> 4;
        int l   = pg & 15;
        float acc[4] = {0.f, 0.f, 0.f, 0.f};
        #pragma unroll
        for (int k = 0; k < 56; ++k) {
            float xv = xl[(h2b * 32 + k) * L_ + l];
            #pragma unroll
            for (int d = 0; d < 4; ++d) {
                int t = k - 8 * d;
                if (t >= 0 && t < EFF_) acc[d] = fmaf(xv, wreg[t], acc[d]);
            }
        }
        #pragma unroll
        for (int d = 0; d < 4; ++d) {
            int h2 = h2b * 4 + d;
            if (h2 < H2_) {
                int f    = c * S_ + h2 * L_ + l;
                int s    = f >> 9;
                int head = (f >> 6) & 7;
                int dh   = f & 63;
                int bh   = b * H_ + head;
                short bv = f2bf(acc[d]);
                if (tz == 0)      qws[((size_t)bh * S_ + s) * D_ + dh] = bv;
                else if (tz == 1) kws[((size_t)bh * S_ + s) * D_ + dh] = bv;
                else              vtws[((size_t)bh * D_ + dh) * SP_ + s] = bv;
            }
        }
    }
}

// ---------------------------------------------------------------------------
// Kernel 3: attention. 2 WAVES per (bh, q-tile), split by key-halves.
// Block = 4 waves = 2 q-tiles. Grid = 64 bh * 31 pairs = 1984 blocks,
// XCD-swizzled so all blocks of one bh land on one XCD (K/V L2-resident).
// ---------------------------------------------------------------------------
__global__ __launch_bounds__(256) void attn_kernel(
    const short* __restrict__ qws, const short* __restrict__ kws,
    const short* __restrict__ vtws, const float* __restrict__ w_out,
    const float* __restrict__ b_out, float* __restrict__ out) {
    __shared__ short plds[4][16 * 40];        // per-wave P repack (5 KB)
    __shared__ float olds[2][16 * OSTR];      // per-pair O combine (8.5 KB)
    __shared__ float sums[2][2][16];

    int w    = threadIdx.x >> 6;
    int lane = threadIdx.x & 63;
    int l16  = lane & 15;
    int g    = lane >> 4;
    int p    = w >> 1;          // pair slot in block
    int h    = w & 1;           // key half

    // XCD swizzle: xcd = blk%8 hosts bh in {xcd, xcd+8, ..., xcd+56}
    int blk = blockIdx.x;       // 0..1983
    int xcd = blk & 7;
    int j   = blk >> 3;         // 0..247
    int bh  = xcd + 8 * (j / 31);
    int pr  = j % 31;           // pair index 0..30
    int qt  = pr * 2 + p;       // 0..61
    bool valid = qt < H2_;
    int s0 = qt * 16;

    bf16x8 q0, q1;
    const short* kbase = kws + ((size_t)bh * S_ + l16) * D_ + g * 8;
    float inv = 0.f;

    if (valid) {
        const short* qb = qws + ((size_t)bh * S_ + s0 + l16) * D_ + g * 8;
        q0 = *(const bf16x8*)qb;
        q1 = *(const bf16x8*)(qb + 32);

        // ---- pass 1 (this wave's key half): partial Z ----
        int t0 = h ? 31 : 0;
        int t1 = h ? 61 : 31;
        float sa = 0.f, sb = 0.f, sc_ = 0.f, sd = 0.f;
        for (int ct = t0; ct < t1; ++ct) {
            const short* kb = kbase + (size_t)ct * 16 * D_;
            bf16x8 k0 = *(const bf16x8*)kb;
            bf16x8 k1 = *(const bf16x8*)(kb + 32);
            f32x4 acc = {0.f, 0.f, 0.f, 0.f};
            acc = __builtin_amdgcn_mfma_f32_16x16x32_bf16(k0, q0, acc, 0, 0, 0);
            acc = __builtin_amdgcn_mfma_f32_16x16x32_bf16(k1, q1, acc, 0, 0, 0);
            sa += __expf(acc[0] * 0.125f);
            sb += __expf(acc[1] * 0.125f);
            sc_ += __expf(acc[2] * 0.125f);
            sd += __expf(acc[3] * 0.125f);
        }
        float sum = (sa + sb) + (sc_ + sd);
        sum += __shfl_xor(sum, 16);
        sum += __shfl_xor(sum, 32);
        if (lane < 16) sums[p][h][l16] = sum;
    }
    __syncthreads();
    if (valid) inv = 1.f / (sums[p][0][l16] + sums[p][1][l16]);

    f32x4 o0 = {0.f,0.f,0.f,0.f}, o1 = {0.f,0.f,0.f,0.f};
    f32x4 o2 = {0.f,0.f,0.f,0.f}, o3 = {0.f,0.f,0.f,0.f};

    if (valid) {
        float* arow = out + XOFF + ((size_t)bh * S_ + s0 + l16) * S_;
        short* pl = &plds[w][0];
        const short* vrow = vtws + ((size_t)bh * D_ + l16) * SP_ + g * 8;

        // ---- pass 2: chunks [15h, 15h+15) ----
        for (int c = 15 * h; c < 15 * h + 15; ++c) {
            #pragma unroll
            for (int t = 0; t < 2; ++t) {
                int ct = 2 * c + t;
                const short* kb = kbase + (size_t)ct * 16 * D_;
                bf16x8 k0 = *(const bf16x8*)kb;
                bf16x8 k1 = *(const bf16x8*)(kb + 32);
                f32x4 acc = {0.f, 0.f, 0.f, 0.f};
                acc = __builtin_amdgcn_mfma_f32_16x16x32_bf16(k0, q0, acc, 0, 0, 0);
                acc = __builtin_amdgcn_mfma_f32_16x16x32_bf16(k1, q1, acc, 0, 0, 0);
                float p0 = __expf(acc[0] * 0.125f) * inv;
                float p1 = __expf(acc[1] * 0.125f) * inv;
                float p2 = __expf(acc[2] * 0.125f) * inv;
                float p3 = __expf(acc[3] * 0.125f) * inv;
                f32x4 pv = {p0, p1, p2, p3};
                __builtin_nontemporal_store(pv, (f32x4*)(arow + ct * 16 + g * 4));
                s16x4 pk = {f2bf(p0), f2bf(p1), f2bf(p2), f2bf(p3)};
                *(s16x4*)(pl + l16 * 40 + t * 16 + g * 4) = pk;
            }
            __threadfence_block();
            bf16x8 pa = *(const bf16x8*)(pl + l16 * 40 + g * 8);
            const short* vb = vrow + c * 32;
            o0 = __builtin_amdgcn_mfma_f32_16x16x32_bf16(pa, *(const bf16x8*)(vb), o0, 0, 0, 0);
            o1 = __builtin_amdgcn_mfma_f32_16x16x32_bf16(pa, *(const bf16x8*)(vb + 16 * SP_), o1, 0, 0, 0);
            o2 = __builtin_amdgcn_mfma_f32_16x16x32_bf16(pa, *(const bf16x8*)(vb + 32 * SP_), o2, 0, 0, 0);
            o3 = __builtin_amdgcn_mfma_f32_16x16x32_bf16(pa, *(const bf16x8*)(vb + 48 * SP_), o3, 0, 0, 0);
        }

        // ---- tail tile 60 (h==1 only) ----
        if (h) {
            const short* kb = kbase + (size_t)60 * 16 * D_;
            bf16x8 k0 = *(const bf16x8*)kb;
            bf16x8 k1 = *(const bf16x8*)(kb + 32);
            f32x4 acc = {0.f, 0.f, 0.f, 0.f};
            acc = __builtin_amdgcn_mfma_f32_16x16x32_bf16(k0, q0, acc, 0, 0, 0);
            acc = __builtin_amdgcn_mfma_f32_16x16x32_bf16(k1, q1, acc, 0, 0, 0);
            float p0 = __expf(acc[0] * 0.125f) * inv;
            float p1 = __expf(acc[1] * 0.125f) * inv;
            float p2 = __expf(acc[2] * 0.125f) * inv;
            float p3 = __expf(acc[3] * 0.125f) * inv;
            f32x4 pv = {p0, p1, p2, p3};
            __builtin_nontemporal_store(pv, (f32x4*)(arow + 60 * 16 + g * 4));
            s16x4 pk = {f2bf(p0), f2bf(p1), f2bf(p2), f2bf(p3)};
            *(s16x4*)(pl + l16 * 40 + g * 4) = pk;
            s16x4 zz = {0, 0, 0, 0};
            *(s16x4*)(pl + l16 * 40 + 16 + g * 4) = zz;
            __threadfence_block();
            bf16x8 pa = *(const bf16x8*)(pl + l16 * 40 + g * 8);
            const short* vb = vrow + 960;
            o0 = __builtin_amdgcn_mfma_f32_16x16x32_bf16(pa, *(const bf16x8*)(vb), o0, 0, 0, 0);
            o1 = __builtin_amdgcn_mfma_f32_16x16x32_bf16(pa, *(const bf16x8*)(vb + 16 * SP_), o1, 0, 0, 0);
            o2 = __builtin_amdgcn_mfma_f32_16x16x32_bf16(pa, *(const bf16x8*)(vb + 32 * SP_), o2, 0, 0, 0);
            o3 = __builtin_amdgcn_mfma_f32_16x16x32_bf16(pa, *(const bf16x8*)(vb + 48 * SP_), o3, 0, 0, 0);
        }

        // ---- h==0 publishes its partial O ----
        if (!h) {
            float* ob = &olds[p][0];
            #pragma unroll
            for (int i = 0; i < 4; ++i) {
                int q = g * 4 + i;
                ob[q * OSTR +  0 + l16] = o0[i];
                ob[q * OSTR + 16 + l16] = o1[i];
                ob[q * OSTR + 32 + l16] = o2[i];
                ob[q * OSTR + 48 + l16] = o3[i];
            }
        }
    }
    __syncthreads();

    // ---- h==1 combines and writes x ----
    if (valid && h) {
        float wo = w_out[0], bo = b_out[0];
        int b = bh >> 3, hh = bh & 7;
        const float* ob = &olds[p][0];
        #pragma unroll
        for (int i = 0; i < 4; ++i) {
            int q = g * 4 + i;
            float* xr = out + ((size_t)b * S_ + s0 + q) * DM_ + hh * D_ + l16;
            __builtin_nontemporal_store((o0[i] + ob[q * OSTR +  0 + l16]) * wo + bo, xr);
            __builtin_nontemporal_store((o1[i] + ob[q * OSTR + 16 + l16]) * wo + bo, xr + 16);
            __builtin_nontemporal_store((o2[i] + ob[q * OSTR + 32 + l16]) * wo + bo, xr + 32);
            __builtin_nontemporal_store((o3[i] + ob[q * OSTR + 48 + l16]) * wo + bo, xr + 48);
        }
    }
}

// ---------------------------------------------------------------------------
extern "C" void kernel_launch(void* const* d_in, const int* in_sizes, int n_in,
                              void* d_out, int out_size, void* d_ws, size_t ws_size,
                              hipStream_t stream) {
    const float* q   = (const float*)d_in[0];
    const float* k   = (const float*)d_in[1];
    const float* v   = (const float*)d_in[2];
    const float* wq  = (const float*)d_in[3];
    const float* wk  = (const float*)d_in[4];
    const float* wv  = (const float*)d_in[5];
    const float* wo  = (const float*)d_in[6];
    const float* bo  = (const float*)d_in[7];

    char* ws = (char*)d_ws;
    float* wbar = (float*)ws;
    short* qws  = (short*)(ws + 196608);
    short* kws  = qws + (size_t)BH_ * S_ * D_;
    short* vtws = kws + (size_t)BH_ * S_ * D_;

    // 192 blocks compute wbar; 256 more zero the V^T pad columns
    wbar_kernel<<<448, 256, 0, stream>>>(wq, wk, wv, wbar, vtws);
    proj_kernel<<<384, 256, 0, stream>>>(q, k, v, wbar, qws, kws, vtws);
    attn_kernel<<<BH_ * 31, 256, 0, stream>>>(qws, kws, vtws, wo, bo,
                                              (float*)d_out);
}

// Round 5
// 162.426 us; speedup vs baseline: 1.8125x; 1.1823x over previous
//
#include <hip/hip_runtime.h>
#include <hip/hip_bf16.h>
#include <cstdint>
#include <cstddef>

// Problem constants
#define B_    8
#define H_    8
#define BH_   64
#define S_    976     // sequence length
#define SP_   992     // padded S (multiple of 32) for PV k-dim
#define D_    64      // head dim
#define DM_   512     // d_model
#define L_    16      // max_len
#define H2_   61      // pooled conv height / q-tiles
#define KW_   25      // conv taps
#define EFF_  32      // effective (conv+pool) taps
#define XOFF  3997696 // x output elements = 8*976*512; attn follows
#define NWB   49152   // 3*512*32 wbar elements
#define OSTR  68      // olds row stride (floats) -> 2-way max bank aliasing

typedef __attribute__((ext_vector_type(8))) short bf16x8;
typedef __attribute__((ext_vector_type(4))) float f32x4;

__device__ __forceinline__ unsigned short f2bfu(float f) {
    union { float f; unsigned u; } v; v.f = f;
    unsigned u = v.u;
    u += 0x7fffu + ((u >> 16) & 1u);   // round-to-nearest-even
    return (unsigned short)(u >> 16);
}
__device__ __forceinline__ unsigned packbf(float a, float b) {
    return (unsigned)f2bfu(a) | ((unsigned)f2bfu(b) << 16);
}
__device__ __forceinline__ float bflo(unsigned u) {
    union { unsigned u; float f; } v; v.u = u << 16; return v.f;
}
__device__ __forceinline__ float bfhi(unsigned u) {
    union { unsigned u; float f; } v; v.u = u & 0xffff0000u; return v.f;
}

// ---------------------------------------------------------------------------
// Kernel 1: fold conv(25)+avgpool(8) into 32-tap filter; spare blocks zero
// the V^T pad columns (s=976..991).
// ---------------------------------------------------------------------------
__global__ __launch_bounds__(256) void wbar_kernel(
    const float* __restrict__ wq, const float* __restrict__ wk,
    const float* __restrict__ wv, float* __restrict__ wbar,
    short* __restrict__ vtws) {
    int idx = blockIdx.x * 256 + threadIdx.x;
    if (idx < NWB) {
        int t  = idx & 31;
        int c  = (idx >> 5) & 511;
        int tz = idx >> 14;
        const float* w = (tz == 0) ? wq : (tz == 1) ? wk : wv;
        int jlo = (t - 24 > 0) ? t - 24 : 0;
        int jhi = (t < 7) ? t : 7;
        float s = 0.f;
        for (int j = jlo; j <= jhi; ++j) s += w[c * KW_ + (t - j)];
        wbar[idx] = s * 0.125f;
    } else {
        int p = idx - NWB;                 // 0..65535
        int bh = p >> 10;
        int dh = (p >> 4) & 63;
        int s  = S_ + (p & 15);
        vtws[((size_t)bh * D_ + dh) * SP_ + s] = 0;
    }
}

// ---------------------------------------------------------------------------
// Kernel 2: projection, register-blocked (unchanged).
// ---------------------------------------------------------------------------
__global__ __launch_bounds__(256) void proj_kernel(
    const float* __restrict__ qin, const float* __restrict__ kin,
    const float* __restrict__ vin, const float* __restrict__ wbar,
    short* __restrict__ qws, short* __restrict__ kws, short* __restrict__ vtws) {
    __shared__ float xl[536 * L_];
    int blk = blockIdx.x;            // grid = 3*8*16 = 384
    int cg  = blk & 15;
    int b   = (blk >> 4) & 7;
    int tz  = blk >> 7;
    const float* x = (tz == 0) ? qin : (tz == 1) ? kin : vin;

    const float4* xb4 = (const float4*)(x + b * DM_ * L_);
    float4* xl4 = (float4*)xl;
    for (int i = threadIdx.x; i < DM_ * L_ / 4; i += 256) xl4[i] = xb4[i];
    for (int i = DM_ * L_ + threadIdx.x; i < 536 * L_; i += 256) xl[i] = 0.f;

    int c_local = threadIdx.x >> 3;
    int plane   = threadIdx.x & 7;
    int c       = cg * 32 + c_local;
    float wreg[EFF_];
    const float4* wb4 = (const float4*)(wbar + ((size_t)tz * DM_ + c) * EFF_);
    #pragma unroll
    for (int i = 0; i < 8; ++i) {
        float4 t4 = wb4[i];
        wreg[4*i+0] = t4.x; wreg[4*i+1] = t4.y;
        wreg[4*i+2] = t4.z; wreg[4*i+3] = t4.w;
    }
    __syncthreads();

    for (int m = 0; m < 32; ++m) {
        int pg  = plane + 8 * m;
        int h2b = pg >> 4;
        int l   = pg & 15;
        float acc[4] = {0.f, 0.f, 0.f, 0.f};
        #pragma unroll
        for (int k = 0; k < 56; ++k) {
            float xv = xl[(h2b * 32 + k) * L_ + l];
            #pragma unroll
            for (int d = 0; d < 4; ++d) {
                int t = k - 8 * d;
                if (t >= 0 && t < EFF_) acc[d] = fmaf(xv, wreg[t], acc[d]);
            }
        }
        #pragma unroll
        for (int d = 0; d < 4; ++d) {
            int h2 = h2b * 4 + d;
            if (h2 < H2_) {
                int f    = c * S_ + h2 * L_ + l;
                int s    = f >> 9;
                int head = (f >> 6) & 7;
                int dh   = f & 63;
                int bh   = b * H_ + head;
                short bv = (short)f2bfu(acc[d]);
                if (tz == 0)      qws[((size_t)bh * S_ + s) * D_ + dh] = bv;
                else if (tz == 1) kws[((size_t)bh * S_ + s) * D_ + dh] = bv;
                else              vtws[((size_t)bh * D_ + dh) * SP_ + s] = bv;
            }
        }
    }
}

// ---------------------------------------------------------------------------
// Kernel 3: attention, single QK pass with register-resident bf16 P.
// 2 waves per (bh, q-tile) split by key halves: h=0 -> tiles 0..29,
// h=1 -> tiles 30..60. Pass A: QK MFMA -> exp -> pack bf16 into pp[31][2]
// (fully unrolled, static indices) + partial sums. Combine sums via LDS.
// Pass B: unpack pp -> NT attn writes (normalized) + PV MFMA on RAW p;
// O normalized by inv[row] in the epilogue (deferred normalization).
// ---------------------------------------------------------------------------
__global__ __launch_bounds__(256) void attn_kernel(
    const short* __restrict__ qws, const short* __restrict__ kws,
    const short* __restrict__ vtws, const float* __restrict__ w_out,
    const float* __restrict__ b_out, float* __restrict__ out) {
    __shared__ short plds[4][16 * 40];        // per-wave P repack (5 KB)
    __shared__ float olds[2][16 * OSTR];      // per-pair O combine (8.5 KB)
    __shared__ float sums[2][2][16];

    int w    = threadIdx.x >> 6;
    int lane = threadIdx.x & 63;
    int l16  = lane & 15;
    int g    = lane >> 4;
    int p    = w >> 1;          // pair slot in block
    int h    = w & 1;           // key half

    // XCD swizzle: xcd = blk%8 hosts bh in {xcd, xcd+8, ..., xcd+56}
    int blk = blockIdx.x;       // 0..1983
    int xcd = blk & 7;
    int j   = blk >> 3;         // 0..247
    int bh  = xcd + 8 * (j / 31);
    int pr  = j % 31;           // pair index 0..30
    int qt  = pr * 2 + p;       // 0..61
    bool valid = qt < H2_;
    int s0 = qt * 16;

    int t0 = h ? 30 : 0;        // first tile of this half
    int nt = h ? 31 : 30;       // tiles in this half

    unsigned pp[31][2];         // packed bf16 exp-scores, register-resident
    float inv = 0.f;

    if (valid) {
        const short* qb = qws + ((size_t)bh * S_ + s0 + l16) * D_ + g * 8;
        bf16x8 q0 = *(const bf16x8*)qb;
        bf16x8 q1 = *(const bf16x8*)(qb + 32);
        const short* kb0 = kws + ((size_t)bh * S_ + t0 * 16 + l16) * D_ + g * 8;

        // ---- pass A: QK^T -> exp -> pack + partial sums ----
        float sa = 0.f, sb = 0.f, sc_ = 0.f, sd = 0.f;
        #pragma unroll
        for (int ct = 0; ct < 31; ++ct) {
            if (ct < nt) {                       // wave-uniform guard
                const short* kb = kb0 + (size_t)ct * 16 * D_;
                bf16x8 k0 = *(const bf16x8*)kb;
                bf16x8 k1 = *(const bf16x8*)(kb + 32);
                f32x4 acc = {0.f, 0.f, 0.f, 0.f};
                acc = __builtin_amdgcn_mfma_f32_16x16x32_bf16(k0, q0, acc, 0, 0, 0);
                acc = __builtin_amdgcn_mfma_f32_16x16x32_bf16(k1, q1, acc, 0, 0, 0);
                float e0 = __expf(acc[0] * 0.125f);
                float e1 = __expf(acc[1] * 0.125f);
                float e2 = __expf(acc[2] * 0.125f);
                float e3 = __expf(acc[3] * 0.125f);
                sa += e0; sb += e1; sc_ += e2; sd += e3;
                pp[ct][0] = packbf(e0, e1);
                pp[ct][1] = packbf(e2, e3);
            }
        }
        float sum = (sa + sb) + (sc_ + sd);
        sum += __shfl_xor(sum, 16);
        sum += __shfl_xor(sum, 32);
        if (lane < 16) sums[p][h][l16] = sum;
    }
    __syncthreads();
    if (valid) inv = 1.f / (sums[p][0][l16] + sums[p][1][l16]);

    f32x4 o0 = {0.f,0.f,0.f,0.f}, o1 = {0.f,0.f,0.f,0.f};
    f32x4 o2 = {0.f,0.f,0.f,0.f}, o3 = {0.f,0.f,0.f,0.f};

    if (valid) {
        float* arow = out + XOFF + ((size_t)bh * S_ + s0 + l16) * S_;
        short* pl = &plds[w][0];
        const short* vrow = vtws + ((size_t)bh * D_ + l16) * SP_ + g * 8;

        // ---- pass B: 15 chunks (2 tiles each) ----
        #pragma unroll
        for (int c = 0; c < 15; ++c) {
            #pragma unroll
            for (int t = 0; t < 2; ++t) {
                int lt = 2 * c + t;            // local tile (const after unroll)
                int gt = t0 + lt;              // global tile
                unsigned u0 = pp[lt][0], u1 = pp[lt][1];
                f32x4 pv = { bflo(u0) * inv, bfhi(u0) * inv,
                             bflo(u1) * inv, bfhi(u1) * inv };
                __builtin_nontemporal_store(pv, (f32x4*)(arow + gt * 16 + g * 4));
                uint2 upk = {u0, u1};
                *(uint2*)(void*)(pl + l16 * 40 + t * 16 + g * 4) = upk;
            }
            __threadfence_block();
            bf16x8 pa = *(const bf16x8*)(pl + l16 * 40 + g * 8);
            const short* vb = vrow + t0 * 16 + c * 32;
            o0 = __builtin_amdgcn_mfma_f32_16x16x32_bf16(pa, *(const bf16x8*)(vb), o0, 0, 0, 0);
            o1 = __builtin_amdgcn_mfma_f32_16x16x32_bf16(pa, *(const bf16x8*)(vb + 16 * SP_), o1, 0, 0, 0);
            o2 = __builtin_amdgcn_mfma_f32_16x16x32_bf16(pa, *(const bf16x8*)(vb + 32 * SP_), o2, 0, 0, 0);
            o3 = __builtin_amdgcn_mfma_f32_16x16x32_bf16(pa, *(const bf16x8*)(vb + 48 * SP_), o3, 0, 0, 0);
        }

        // ---- tail tile 60 (h==1 only, local tile 30) ----
        if (h) {
            unsigned u0 = pp[30][0], u1 = pp[30][1];
            f32x4 pv = { bflo(u0) * inv, bfhi(u0) * inv,
                         bflo(u1) * inv, bfhi(u1) * inv };
            __builtin_nontemporal_store(pv, (f32x4*)(arow + 60 * 16 + g * 4));
            uint2 upk = {u0, u1};
            *(uint2*)(void*)(pl + l16 * 40 + g * 4) = upk;
            uint2 zz = {0u, 0u};
            *(uint2*)(void*)(pl + l16 * 40 + 16 + g * 4) = zz;
            __threadfence_block();
            bf16x8 pa = *(const bf16x8*)(pl + l16 * 40 + g * 8);
            const short* vb = vrow + 960;      // keys 960..991 (V pad zeroed)
            o0 = __builtin_amdgcn_mfma_f32_16x16x32_bf16(pa, *(const bf16x8*)(vb), o0, 0, 0, 0);
            o1 = __builtin_amdgcn_mfma_f32_16x16x32_bf16(pa, *(const bf16x8*)(vb + 16 * SP_), o1, 0, 0, 0);
            o2 = __builtin_amdgcn_mfma_f32_16x16x32_bf16(pa, *(const bf16x8*)(vb + 32 * SP_), o2, 0, 0, 0);
            o3 = __builtin_amdgcn_mfma_f32_16x16x32_bf16(pa, *(const bf16x8*)(vb + 48 * SP_), o3, 0, 0, 0);
        }

        // ---- h==0 publishes its raw partial O ----
        if (!h) {
            float* ob = &olds[p][0];
            #pragma unroll
            for (int i = 0; i < 4; ++i) {
                int q = g * 4 + i;
                ob[q * OSTR +  0 + l16] = o0[i];
                ob[q * OSTR + 16 + l16] = o1[i];
                ob[q * OSTR + 32 + l16] = o2[i];
                ob[q * OSTR + 48 + l16] = o3[i];
            }
        }
    }
    __syncthreads();

    // ---- h==1 combines, normalizes (deferred inv), writes x ----
    if (valid && h) {
        float wo = w_out[0], bo = b_out[0];
        int b = bh >> 3, hh = bh & 7;
        const float* ob = &olds[p][0];
        #pragma unroll
        for (int i = 0; i < 4; ++i) {
            int q = g * 4 + i;
            float invr = __shfl(inv, q);       // inv of query row q
            float s1 = invr * wo;
            float* xr = out + ((size_t)b * S_ + s0 + q) * DM_ + hh * D_ + l16;
            xr[0]  = (o0[i] + ob[q * OSTR +  0 + l16]) * s1 + bo;
            xr[16] = (o1[i] + ob[q * OSTR + 16 + l16]) * s1 + bo;
            xr[32] = (o2[i] + ob[q * OSTR + 32 + l16]) * s1 + bo;
            xr[48] = (o3[i] + ob[q * OSTR + 48 + l16]) * s1 + bo;
        }
    }
}

// ---------------------------------------------------------------------------
extern "C" void kernel_launch(void* const* d_in, const int* in_sizes, int n_in,
                              void* d_out, int out_size, void* d_ws, size_t ws_size,
                              hipStream_t stream) {
    const float* q   = (const float*)d_in[0];
    const float* k   = (const float*)d_in[1];
    const float* v   = (const float*)d_in[2];
    const float* wq  = (const float*)d_in[3];
    const float* wk  = (const float*)d_in[4];
    const float* wv  = (const float*)d_in[5];
    const float* wo  = (const float*)d_in[6];
    const float* bo  = (const float*)d_in[7];

    char* ws = (char*)d_ws;
    float* wbar = (float*)ws;
    short* qws  = (short*)(ws + 196608);
    short* kws  = qws + (size_t)BH_ * S_ * D_;
    short* vtws = kws + (size_t)BH_ * S_ * D_;

    // 192 blocks compute wbar; 256 more zero the V^T pad columns
    wbar_kernel<<<448, 256, 0, stream>>>(wq, wk, wv, wbar, vtws);
    proj_kernel<<<384, 256, 0, stream>>>(q, k, v, wbar, qws, kws, vtws);
    attn_kernel<<<BH_ * 31, 256, 0, stream>>>(qws, kws, vtws, wo, bo,
                                              (float*)d_out);
}

// Round 6
// 159.785 us; speedup vs baseline: 1.8425x; 1.0165x over previous
//
#include <hip/hip_runtime.h>
#include <hip/hip_bf16.h>
#include <cstdint>
#include <cstddef>

// Problem constants
#define B_    8
#define H_    8
#define BH_   64
#define S_    976     // sequence length
#define SP_   992     // padded S (multiple of 32) for PV k-dim
#define D_    64      // head dim
#define DM_   512     // d_model
#define L_    16      // max_len
#define H2_   61      // pooled conv height / q-tiles
#define KW_   25      // conv taps
#define EFF_  32      // effective (conv+pool) taps
#define XOFF  3997696 // x output elements = 8*976*512; attn follows
#define NWB   49152   // 3*512*32 wbar elements
#define OSTR  68      // olds row stride (floats) -> 2-way max bank aliasing

typedef __attribute__((ext_vector_type(8))) short bf16x8;
typedef __attribute__((ext_vector_type(4))) float f32x4;

__device__ __forceinline__ unsigned short f2bfu(float f) {
    union { float f; unsigned u; } v; v.f = f;
    unsigned u = v.u;
    u += 0x7fffu + ((u >> 16) & 1u);   // round-to-nearest-even
    return (unsigned short)(u >> 16);
}
__device__ __forceinline__ unsigned packbf(float a, float b) {
    return (unsigned)f2bfu(a) | ((unsigned)f2bfu(b) << 16);
}
__device__ __forceinline__ float bflo(unsigned u) {
    union { unsigned u; float f; } v; v.u = u << 16; return v.f;
}
__device__ __forceinline__ float bfhi(unsigned u) {
    union { unsigned u; float f; } v; v.u = u & 0xffff0000u; return v.f;
}

// ---------------------------------------------------------------------------
// Kernel 1: fold conv(25)+avgpool(8) into 32-tap filter; spare blocks zero
// the V^T pad columns (s=976..991).
// ---------------------------------------------------------------------------
__global__ __launch_bounds__(256) void wbar_kernel(
    const float* __restrict__ wq, const float* __restrict__ wk,
    const float* __restrict__ wv, float* __restrict__ wbar,
    short* __restrict__ vtws) {
    int idx = blockIdx.x * 256 + threadIdx.x;
    if (idx < NWB) {
        int t  = idx & 31;
        int c  = (idx >> 5) & 511;
        int tz = idx >> 14;
        const float* w = (tz == 0) ? wq : (tz == 1) ? wk : wv;
        int jlo = (t - 24 > 0) ? t - 24 : 0;
        int jhi = (t < 7) ? t : 7;
        float s = 0.f;
        for (int j = jlo; j <= jhi; ++j) s += w[c * KW_ + (t - j)];
        wbar[idx] = s * 0.125f;
    } else {
        int p = idx - NWB;                 // 0..65535
        int bh = p >> 10;
        int dh = (p >> 4) & 63;
        int s  = S_ + (p & 15);
        vtws[((size_t)bh * D_ + dh) * SP_ + s] = 0;
    }
}

// ---------------------------------------------------------------------------
// Kernel 2: projection, register-blocked (unchanged).
// ---------------------------------------------------------------------------
__global__ __launch_bounds__(256) void proj_kernel(
    const float* __restrict__ qin, const float* __restrict__ kin,
    const float* __restrict__ vin, const float* __restrict__ wbar,
    short* __restrict__ qws, short* __restrict__ kws, short* __restrict__ vtws) {
    __shared__ float xl[536 * L_];
    int blk = blockIdx.x;            // grid = 3*8*16 = 384
    int cg  = blk & 15;
    int b   = (blk >> 4) & 7;
    int tz  = blk >> 7;
    const float* x = (tz == 0) ? qin : (tz == 1) ? kin : vin;

    const float4* xb4 = (const float4*)(x + b * DM_ * L_);
    float4* xl4 = (float4*)xl;
    for (int i = threadIdx.x; i < DM_ * L_ / 4; i += 256) xl4[i] = xb4[i];
    for (int i = DM_ * L_ + threadIdx.x; i < 536 * L_; i += 256) xl[i] = 0.f;

    int c_local = threadIdx.x >> 3;
    int plane   = threadIdx.x & 7;
    int c       = cg * 32 + c_local;
    float wreg[EFF_];
    const float4* wb4 = (const float4*)(wbar + ((size_t)tz * DM_ + c) * EFF_);
    #pragma unroll
    for (int i = 0; i < 8; ++i) {
        float4 t4 = wb4[i];
        wreg[4*i+0] = t4.x; wreg[4*i+1] = t4.y;
        wreg[4*i+2] = t4.z; wreg[4*i+3] = t4.w;
    }
    __syncthreads();

    for (int m = 0; m < 32; ++m) {
        int pg  = plane + 8 * m;
        int h2b = pg >> 4;
        int l   = pg & 15;
        float acc[4] = {0.f, 0.f, 0.f, 0.f};
        #pragma unroll
        for (int k = 0; k < 56; ++k) {
            float xv = xl[(h2b * 32 + k) * L_ + l];
            #pragma unroll
            for (int d = 0; d < 4; ++d) {
                int t = k - 8 * d;
                if (t >= 0 && t < EFF_) acc[d] = fmaf(xv, wreg[t], acc[d]);
            }
        }
        #pragma unroll
        for (int d = 0; d < 4; ++d) {
            int h2 = h2b * 4 + d;
            if (h2 < H2_) {
                int f    = c * S_ + h2 * L_ + l;
                int s    = f >> 9;
                int head = (f >> 6) & 7;
                int dh   = f & 63;
                int bh   = b * H_ + head;
                short bv = (short)f2bfu(acc[d]);
                if (tz == 0)      qws[((size_t)bh * S_ + s) * D_ + dh] = bv;
                else if (tz == 1) kws[((size_t)bh * S_ + s) * D_ + dh] = bv;
                else              vtws[((size_t)bh * D_ + dh) * SP_ + s] = bv;
            }
        }
    }
}

// ---------------------------------------------------------------------------
// Kernel 3: attention. ONE BLOCK per (bh, q-tile); 4 waves, each owning a
// key quarter: w0 tiles 0..15, w1 16..30, w2 31..45, w3 46..60.
// Pass A: QK MFMA -> exp -> bf16-packed pp[16][2] (registers) + partial sums.
// Combine denominators via LDS. Pass B: NT attn writes + PV MFMA on raw P
// (phantom zero-P half-chunk finishes odd tile counts). O combined via LDS;
// w3 normalizes (deferred inv) and writes x.
// ---------------------------------------------------------------------------
__global__ __launch_bounds__(256) void attn_kernel(
    const short* __restrict__ qws, const short* __restrict__ kws,
    const short* __restrict__ vtws, const float* __restrict__ w_out,
    const float* __restrict__ b_out, float* __restrict__ out) {
    __shared__ short plds[4][16 * 40];        // per-wave P repack (5 KB)
    __shared__ float olds[3][16 * OSTR];      // partial-O publish (13 KB)
    __shared__ float sums[4][16];

    int w    = threadIdx.x >> 6;
    int lane = threadIdx.x & 63;
    int l16  = lane & 15;
    int g    = lane >> 4;

    // XCD swizzle: xcd = blk%8 hosts bh in {xcd, xcd+8, ..., xcd+56}
    int blk = blockIdx.x;       // 0..3903
    int xcd = blk & 7;
    int j   = blk >> 3;         // 0..487
    int bh  = xcd + 8 * (j / H2_);
    int qt  = j % H2_;          // 0..60
    int s0  = qt * 16;

    int t0 = (w == 0) ? 0 : 16 + (w - 1) * 15;   // 0,16,31,46
    int nt = (w == 0) ? 16 : 15;

    unsigned pp[16][2];         // packed bf16 exp-scores, register-resident

    const short* qb = qws + ((size_t)bh * S_ + s0 + l16) * D_ + g * 8;
    bf16x8 q0 = *(const bf16x8*)qb;
    bf16x8 q1 = *(const bf16x8*)(qb + 32);
    const short* kb0 = kws + ((size_t)bh * S_ + t0 * 16 + l16) * D_ + g * 8;

    // ---- pass A: QK^T -> exp -> pack + partial sums ----
    float sa = 0.f, sb = 0.f, sc_ = 0.f, sd = 0.f;
    #pragma unroll
    for (int ct = 0; ct < 16; ++ct) {
        if (ct < nt) {                       // wave-uniform guard
            const short* kb = kb0 + (size_t)ct * 16 * D_;
            bf16x8 k0 = *(const bf16x8*)kb;
            bf16x8 k1 = *(const bf16x8*)(kb + 32);
            f32x4 acc = {0.f, 0.f, 0.f, 0.f};
            acc = __builtin_amdgcn_mfma_f32_16x16x32_bf16(k0, q0, acc, 0, 0, 0);
            acc = __builtin_amdgcn_mfma_f32_16x16x32_bf16(k1, q1, acc, 0, 0, 0);
            float e0 = __expf(acc[0] * 0.125f);
            float e1 = __expf(acc[1] * 0.125f);
            float e2 = __expf(acc[2] * 0.125f);
            float e3 = __expf(acc[3] * 0.125f);
            sa += e0; sb += e1; sc_ += e2; sd += e3;
            pp[ct][0] = packbf(e0, e1);
            pp[ct][1] = packbf(e2, e3);
        }
    }
    float sum = (sa + sb) + (sc_ + sd);
    sum += __shfl_xor(sum, 16);
    sum += __shfl_xor(sum, 32);
    if (lane < 16) sums[w][l16] = sum;
    __syncthreads();
    float inv = 1.f / ((sums[0][l16] + sums[1][l16]) +
                       (sums[2][l16] + sums[3][l16]));

    f32x4 o0 = {0.f,0.f,0.f,0.f}, o1 = {0.f,0.f,0.f,0.f};
    f32x4 o2 = {0.f,0.f,0.f,0.f}, o3 = {0.f,0.f,0.f,0.f};

    float* arow = out + XOFF + ((size_t)bh * S_ + s0 + l16) * S_;
    short* pl = &plds[w][0];
    const short* vrow = vtws + ((size_t)bh * D_ + l16) * SP_ + g * 8;

    // ---- pass B: full chunks (2 tiles each); w0 has 8, others 7+tail ----
    int nc = (w == 0) ? 8 : 7;
    #pragma unroll
    for (int c = 0; c < 8; ++c) {
        if (c < nc) {
            #pragma unroll
            for (int t = 0; t < 2; ++t) {
                int lt = 2 * c + t;            // static after unroll
                int gt = t0 + lt;
                unsigned u0 = pp[lt][0], u1 = pp[lt][1];
                f32x4 pv = { bflo(u0) * inv, bfhi(u0) * inv,
                             bflo(u1) * inv, bfhi(u1) * inv };
                __builtin_nontemporal_store(pv, (f32x4*)(arow + gt * 16 + g * 4));
                uint2 upk = {u0, u1};
                *(uint2*)(void*)(pl + l16 * 40 + t * 16 + g * 4) = upk;
            }
            __threadfence_block();
            bf16x8 pa = *(const bf16x8*)(pl + l16 * 40 + g * 8);
            const short* vb = vrow + t0 * 16 + c * 32;
            o0 = __builtin_amdgcn_mfma_f32_16x16x32_bf16(pa, *(const bf16x8*)(vb), o0, 0, 0, 0);
            o1 = __builtin_amdgcn_mfma_f32_16x16x32_bf16(pa, *(const bf16x8*)(vb + 16 * SP_), o1, 0, 0, 0);
            o2 = __builtin_amdgcn_mfma_f32_16x16x32_bf16(pa, *(const bf16x8*)(vb + 32 * SP_), o2, 0, 0, 0);
            o3 = __builtin_amdgcn_mfma_f32_16x16x32_bf16(pa, *(const bf16x8*)(vb + 48 * SP_), o3, 0, 0, 0);
        }
    }

    // ---- tail: odd 15th tile for w>0, phantom zero-P upper half ----
    if (w != 0) {
        unsigned u0 = pp[14][0], u1 = pp[14][1];
        f32x4 pv = { bflo(u0) * inv, bfhi(u0) * inv,
                     bflo(u1) * inv, bfhi(u1) * inv };
        __builtin_nontemporal_store(pv, (f32x4*)(arow + (t0 + 14) * 16 + g * 4));
        uint2 upk = {u0, u1};
        *(uint2*)(void*)(pl + l16 * 40 + g * 4) = upk;
        uint2 zz = {0u, 0u};
        *(uint2*)(void*)(pl + l16 * 40 + 16 + g * 4) = zz;   // P=0 -> no contrib
        __threadfence_block();
        bf16x8 pa = *(const bf16x8*)(pl + l16 * 40 + g * 8);
        const short* vb = vrow + t0 * 16 + 224;              // keys t0*16+224..+255
        o0 = __builtin_amdgcn_mfma_f32_16x16x32_bf16(pa, *(const bf16x8*)(vb), o0, 0, 0, 0);
        o1 = __builtin_amdgcn_mfma_f32_16x16x32_bf16(pa, *(const bf16x8*)(vb + 16 * SP_), o1, 0, 0, 0);
        o2 = __builtin_amdgcn_mfma_f32_16x16x32_bf16(pa, *(const bf16x8*)(vb + 32 * SP_), o2, 0, 0, 0);
        o3 = __builtin_amdgcn_mfma_f32_16x16x32_bf16(pa, *(const bf16x8*)(vb + 48 * SP_), o3, 0, 0, 0);
    }

    // ---- waves 0..2 publish raw partial O ----
    if (w != 3) {
        float* ob = &olds[w][0];
        #pragma unroll
        for (int i = 0; i < 4; ++i) {
            int q = g * 4 + i;
            ob[q * OSTR +  0 + l16] = o0[i];
            ob[q * OSTR + 16 + l16] = o1[i];
            ob[q * OSTR + 32 + l16] = o2[i];
            ob[q * OSTR + 48 + l16] = o3[i];
        }
    }
    __syncthreads();

    // ---- w3 combines, normalizes (deferred inv), writes x ----
    if (w == 3) {
        float wo = w_out[0], bo = b_out[0];
        int b = bh >> 3, hh = bh & 7;
        #pragma unroll
        for (int i = 0; i < 4; ++i) {
            int q = g * 4 + i;
            float invr = __shfl(inv, q);       // inv of query row q
            float s1 = invr * wo;
            float* xr = out + ((size_t)b * S_ + s0 + q) * DM_ + hh * D_ + l16;
            int o = q * OSTR + l16;
            xr[0]  = (o0[i] + olds[0][o +  0] + olds[1][o +  0] + olds[2][o +  0]) * s1 + bo;
            xr[16] = (o1[i] + olds[0][o + 16] + olds[1][o + 16] + olds[2][o + 16]) * s1 + bo;
            xr[32] = (o2[i] + olds[0][o + 32] + olds[1][o + 32] + olds[2][o + 32]) * s1 + bo;
            xr[48] = (o3[i] + olds[0][o + 48] + olds[1][o + 48] + olds[2][o + 48]) * s1 + bo;
        }
    }
}

// ---------------------------------------------------------------------------
extern "C" void kernel_launch(void* const* d_in, const int* in_sizes, int n_in,
                              void* d_out, int out_size, void* d_ws, size_t ws_size,
                              hipStream_t stream) {
    const float* q   = (const float*)d_in[0];
    const float* k   = (const float*)d_in[1];
    const float* v   = (const float*)d_in[2];
    const float* wq  = (const float*)d_in[3];
    const float* wk  = (const float*)d_in[4];
    const float* wv  = (const float*)d_in[5];
    const float* wo  = (const float*)d_in[6];
    const float* bo  = (const float*)d_in[7];

    char* ws = (char*)d_ws;
    float* wbar = (float*)ws;
    short* qws  = (short*)(ws + 196608);
    short* kws  = qws + (size_t)BH_ * S_ * D_;
    short* vtws = kws + (size_t)BH_ * S_ * D_;

    // 192 blocks compute wbar; 256 more zero the V^T pad columns
    wbar_kernel<<<448, 256, 0, stream>>>(wq, wk, wv, wbar, vtws);
    proj_kernel<<<384, 256, 0, stream>>>(q, k, v, wbar, qws, kws, vtws);
    attn_kernel<<<BH_ * H2_, 256, 0, stream>>>(qws, kws, vtws, wo, bo,
                                               (float*)d_out);
}